// Round 13
// baseline (244.937 us; speedup 1.0000x reference)
//
#include <hip/hip_runtime.h>
#include <hip/hip_bf16.h>

typedef __bf16 bf16x8 __attribute__((ext_vector_type(8)));
typedef float f32x4 __attribute__((ext_vector_type(4)));

static constexpr size_t MB = 1024 * 1024;

__device__ __forceinline__ void gload16(const void* g, void* l) {
  __builtin_amdgcn_global_load_lds((const __attribute__((address_space(1))) unsigned int*)g,
                                   (__attribute__((address_space(3))) unsigned int*)l,
                                   16, 0, 0);
}

__device__ __forceinline__ unsigned short f2b(float x) {
  union { __hip_bfloat16 h; unsigned short u; } cv;
  cv.h = __float2bfloat16(x);
  return cv.u;
}

// ------------- pack/transpose: X -> bf16 (vectorized) + tiled weight transposes -------------
__global__ __launch_bounds__(256) void pt_k(
    const float* __restrict__ X,
    const float* __restrict__ Wq, const float* __restrict__ Wk, const float* __restrict__ Wv,
    const float* __restrict__ Wo, const float* __restrict__ W1, const float* __restrict__ W2,
    __hip_bfloat16* __restrict__ XB, __hip_bfloat16* __restrict__ WQKVT,
    __hip_bfloat16* __restrict__ WOT, __hip_bfloat16* __restrict__ W1T,
    __hip_bfloat16* __restrict__ W2T)
{
  __shared__ float tile[64][65];
  const int bid = blockIdx.x, tid = threadIdx.x;
  if (bid < 4096) {
    size_t i = (size_t)bid * 2048 + tid * 8;
    float4 a0 = *(const float4*)(X + i);
    float4 a1 = *(const float4*)(X + i + 4);
    unsigned int w0 = (unsigned)f2b(a0.x) | ((unsigned)f2b(a0.y) << 16);
    unsigned int w1 = (unsigned)f2b(a0.z) | ((unsigned)f2b(a0.w) << 16);
    unsigned int w2 = (unsigned)f2b(a1.x) | ((unsigned)f2b(a1.y) << 16);
    unsigned int w3 = (unsigned)f2b(a1.z) | ((unsigned)f2b(a1.w) << 16);
    uint4 p; p.x = w0; p.y = w1; p.z = w2; p.w = w3;
    *(uint4*)(XB + i) = p;
    return;
  }
  int tb = bid - 4096;
  const float* in; __hip_bfloat16* out; int R, C, tt;
  if (tb < 64)       { in = Wq; out = WQKVT;          R = 512;  C = 512;  tt = tb; }
  else if (tb < 128) { in = Wk; out = WQKVT + 262144; R = 512;  C = 512;  tt = tb - 64; }
  else if (tb < 192) { in = Wv; out = WQKVT + 524288; R = 512;  C = 512;  tt = tb - 128; }
  else if (tb < 256) { in = Wo; out = WOT;            R = 512;  C = 512;  tt = tb - 192; }
  else if (tb < 512) { in = W1; out = W1T;            R = 512;  C = 2048; tt = tb - 256; }
  else               { in = W2; out = W2T;            R = 2048; C = 512;  tt = tb - 512; }
  const int ct = C >> 6;
  const int r0 = (tt / ct) << 6, c0 = (tt % ct) << 6;
  const int tx = tid & 63, ty = tid >> 6;
  #pragma unroll
  for (int j = 0; j < 16; ++j) {
    int r = ty * 16 + j;
    tile[r][tx] = in[(size_t)(r0 + r) * C + c0 + tx];
  }
  __syncthreads();
  #pragma unroll
  for (int j = 0; j < 16; ++j) {
    int c = ty * 16 + j;
    out[(size_t)(c0 + c) * R + r0 + tx] = __float2bfloat16(tile[tx][c]);
  }
}

// ---------------- 128x128 bf16 MFMA GEMM (proven 2-barrier structure) ----------------
// Used for Wo and FFN2 (grids whose 256^2 version would leave half the CUs idle).
// EPI 1: +bias -> bf16; EPI 3: +bias+residual(bf16) -> bf16.
template<int EPI>
__global__ __launch_bounds__(256) void gemm_k(
    const __hip_bfloat16* __restrict__ A,
    const __hip_bfloat16* __restrict__ Bt,
    int M, int N, int K,
    const float* __restrict__ bias0,
    const __hip_bfloat16* __restrict__ resid,
    void* __restrict__ o0)
{
  __shared__ __align__(16) char lA[128 * 64 * 2];
  __shared__ __align__(16) char lB[128 * 64 * 2];
  const int tid = threadIdx.x;
  const int wv = tid >> 6, ln = tid & 63;
  const int g = ln >> 4, q16 = ln & 15;
  const int mT = M >> 7;
  const int bm = blockIdx.x % mT, bn = blockIdx.x / mT;
  const int row0 = bm << 7, col0 = bn << 7;
  const int wm = wv >> 1, wn = wv & 1;
  const int ktn = K >> 6;

  f32x4 acc[4][4] = {};

  for (int kt = 0; kt < ktn; ++kt) {
    #pragma unroll
    for (int c4 = 0; c4 < 4; ++c4) {
      int c = wv * 4 + c4;
      int o = c * 1024 + ln * 16;
      int r = o >> 7;
      int slot = (o >> 4) & 7;
      int koff = kt * 64 + ((slot ^ (r & 7)) << 3);
      gload16(A + (size_t)(row0 + r) * K + koff, lA + c * 1024);
      gload16(Bt + (size_t)(col0 + r) * K + koff, lB + c * 1024);
    }
    __syncthreads();
    #pragma unroll
    for (int ks = 0; ks < 2; ++ks) {
      bf16x8 af[4], bfr[4];
      #pragma unroll
      for (int m = 0; m < 4; ++m) {
        int r = wm * 64 + m * 16 + q16;
        af[m] = *(const bf16x8*)(lA + r * 128 + (((4 * ks + g) ^ (r & 7)) << 4));
      }
      #pragma unroll
      for (int n = 0; n < 4; ++n) {
        int r = wn * 64 + n * 16 + q16;
        bfr[n] = *(const bf16x8*)(lB + r * 128 + (((4 * ks + g) ^ (r & 7)) << 4));
      }
      #pragma unroll
      for (int m = 0; m < 4; ++m) {
        #pragma unroll
        for (int n = 0; n < 4; ++n) {
          acc[m][n] = __builtin_amdgcn_mfma_f32_16x16x32_bf16(af[m], bfr[n], acc[m][n], 0, 0, 0);
        }
      }
    }
    __syncthreads();
  }

  #pragma unroll
  for (int m = 0; m < 4; ++m) {
    int rowb = row0 + wm * 64 + m * 16 + g * 4;
    #pragma unroll
    for (int n = 0; n < 4; ++n) {
      int col = col0 + wn * 64 + n * 16 + q16;
      f32x4 v = acc[m][n];
      float bb = bias0[col];
      __hip_bfloat16* O = (__hip_bfloat16*)o0;
      #pragma unroll
      for (int r = 0; r < 4; ++r) {
        float x = v[r] + bb;
        if constexpr (EPI == 3) x += (float)resid[(size_t)(rowb + r) * N + col];
        O[(size_t)(rowb + r) * N + col] = __float2bfloat16(x);
      }
    }
  }
}

// ---------------- 256x256 bf16 MFMA GEMM, 8-phase counted-vmcnt schedule ----------------
// 8 waves (2M x 4N), per-wave C = 128x64, BK=64, 128KB LDS (2 tile buffers).
// Per tile t: 4 phases (mq, ks); stage tile t+1 interleaved as {Bh0, Bh1, A-U0, A-U1}
// where A-U u = rows u*64..+63 and 128+u*64..+63 (the rows both wm-halves read in
// phase-pair u). Gates (per-wave vmcnt queue accounting, steady state 8 loads/wave):
//   p0 gate vmcnt(2): oldest 6 = {Bh0,Bh1,AU0}(t) landed; AU1(t) may fly.
//   p1 gate vmcnt(2): outstanding <= {AU1(t), Bh0(t+1)}; oldest 2 = AU1(t) landed.
//   last tile: vmcnt(0) at both gates. Stages always target buf ~(t&1) -> WAR-safe.
// EPI 0: QKV scatter (o0=Q, o1=K, o2=V^T); EPI 2: +bias+relu -> bf16.
template<int EPI>
__global__ __launch_bounds__(512, 2) void gemm256_k(
    const __hip_bfloat16* __restrict__ A,
    const __hip_bfloat16* __restrict__ Bt,
    int M, int N, int K,
    const float* __restrict__ bias0, const float* __restrict__ bias1, const float* __restrict__ bias2,
    void* __restrict__ o0, void* __restrict__ o1, void* __restrict__ o2)
{
  __shared__ __align__(16) char lA[2][32768];
  __shared__ __align__(16) char lB[2][32768];
  const int tid = threadIdx.x;
  const int wv = tid >> 6, ln = tid & 63;
  const int g = ln >> 4, q16 = ln & 15;
  const int wm = wv >> 2, wn = wv & 3;
  const int mT = M >> 8;
  const int bm = blockIdx.x % mT, bn = blockIdx.x / mT;
  const int row0 = bm << 8, col0 = bn << 8;
  const int ktn = K >> 6;

  f32x4 acc[8][4] = {};

  const int c0 = wv * 2;                   // this wave's first 1KB chunk (of 16)
  const int rln = ln >> 3;                 // row offset within an 8-row chunk
  const int sw8 = ((ln & 7) ^ rln) << 3;   // pre-swizzled k-offset (elements)

  // stage B-half h of tile kt: rows h*128 + c*8 (+rln)
  auto stageB = [&](int kt, int h) {
    #pragma unroll
    for (int cc = 0; cc < 2; ++cc) {
      int c = c0 + cc;
      int rb = h * 128 + c * 8;
      gload16(Bt + (size_t)(col0 + rb + rln) * K + kt * 64 + sw8, lB[kt & 1] + rb * 128);
    }
  };
  // stage A-unit u: rows u*64 + (c&7)*8 (+128 for c>=8) (+rln)
  auto stageA = [&](int kt, int u) {
    #pragma unroll
    for (int cc = 0; cc < 2; ++cc) {
      int c = c0 + cc;
      int rb = u * 64 + (c & 7) * 8 + ((c >> 3) << 7);
      gload16(A + (size_t)(row0 + rb + rln) * K + kt * 64 + sw8, lA[kt & 1] + rb * 128);
    }
  };

  auto readA = [&](int b, int m, int ks) -> bf16x8 {
    int r = wm * 128 + m * 16 + q16;
    return *(const bf16x8*)(lA[b] + r * 128 + (((ks * 4 + g) ^ (q16 & 7)) << 4));
  };
  auto readB = [&](int b, int n, int ks) -> bf16x8 {
    int r = wn * 64 + n * 16 + q16;
    return *(const bf16x8*)(lB[b] + r * 128 + (((ks * 4 + g) ^ (q16 & 7)) << 4));
  };

  // prologue: tile 0 fully in flight (8 loads/wave)
  stageB(0, 0); stageB(0, 1); stageA(0, 0); stageA(0, 1);

  for (int kt = 0; kt < ktn; ++kt) {
    const int b = kt & 1;
    const bool more = (kt + 1) < ktn;
    bf16x8 bf0[4], bf1[4];

    // ---- gate p0: B(kt) + A-U0(kt) landed ----
    if (more) { asm volatile("s_waitcnt vmcnt(2)" ::: "memory"); }
    else      { asm volatile("s_waitcnt vmcnt(0)" ::: "memory"); }
    __builtin_amdgcn_s_barrier();
    __builtin_amdgcn_sched_barrier(0);
    if (more) stageB(kt + 1, 0);
    { // phase 0: m 0..3, ks 0; load bf0
      bf16x8 a0 = readA(b, 0, 0), a1 = readA(b, 1, 0), a2 = readA(b, 2, 0), a3 = readA(b, 3, 0);
      bf0[0] = readB(b, 0, 0); bf0[1] = readB(b, 1, 0); bf0[2] = readB(b, 2, 0); bf0[3] = readB(b, 3, 0);
      asm volatile("s_waitcnt lgkmcnt(0)" ::: "memory");
      __builtin_amdgcn_sched_barrier(0);
      __builtin_amdgcn_s_setprio(1);
      #pragma unroll
      for (int n = 0; n < 4; ++n) {
        acc[0][n] = __builtin_amdgcn_mfma_f32_16x16x32_bf16(a0, bf0[n], acc[0][n], 0, 0, 0);
        acc[1][n] = __builtin_amdgcn_mfma_f32_16x16x32_bf16(a1, bf0[n], acc[1][n], 0, 0, 0);
        acc[2][n] = __builtin_amdgcn_mfma_f32_16x16x32_bf16(a2, bf0[n], acc[2][n], 0, 0, 0);
        acc[3][n] = __builtin_amdgcn_mfma_f32_16x16x32_bf16(a3, bf0[n], acc[3][n], 0, 0, 0);
      }
      __builtin_amdgcn_s_setprio(0);
    }

    // ---- gate p1: A-U1(kt) landed ----
    if (more) { asm volatile("s_waitcnt vmcnt(2)" ::: "memory"); }
    else      { asm volatile("s_waitcnt vmcnt(0)" ::: "memory"); }
    __builtin_amdgcn_s_barrier();
    __builtin_amdgcn_sched_barrier(0);
    if (more) stageB(kt + 1, 1);
    { // phase 1: m 4..7, ks 0 (reuse bf0)
      bf16x8 a0 = readA(b, 4, 0), a1 = readA(b, 5, 0), a2 = readA(b, 6, 0), a3 = readA(b, 7, 0);
      asm volatile("s_waitcnt lgkmcnt(0)" ::: "memory");
      __builtin_amdgcn_sched_barrier(0);
      __builtin_amdgcn_s_setprio(1);
      #pragma unroll
      for (int n = 0; n < 4; ++n) {
        acc[4][n] = __builtin_amdgcn_mfma_f32_16x16x32_bf16(a0, bf0[n], acc[4][n], 0, 0, 0);
        acc[5][n] = __builtin_amdgcn_mfma_f32_16x16x32_bf16(a1, bf0[n], acc[5][n], 0, 0, 0);
        acc[6][n] = __builtin_amdgcn_mfma_f32_16x16x32_bf16(a2, bf0[n], acc[6][n], 0, 0, 0);
        acc[7][n] = __builtin_amdgcn_mfma_f32_16x16x32_bf16(a3, bf0[n], acc[7][n], 0, 0, 0);
      }
      __builtin_amdgcn_s_setprio(0);
    }

    if (more) stageA(kt + 1, 0);
    { // phase 2: m 0..3, ks 1; load bf1
      bf16x8 a0 = readA(b, 0, 1), a1 = readA(b, 1, 1), a2 = readA(b, 2, 1), a3 = readA(b, 3, 1);
      bf1[0] = readB(b, 0, 1); bf1[1] = readB(b, 1, 1); bf1[2] = readB(b, 2, 1); bf1[3] = readB(b, 3, 1);
      asm volatile("s_waitcnt lgkmcnt(0)" ::: "memory");
      __builtin_amdgcn_sched_barrier(0);
      __builtin_amdgcn_s_setprio(1);
      #pragma unroll
      for (int n = 0; n < 4; ++n) {
        acc[0][n] = __builtin_amdgcn_mfma_f32_16x16x32_bf16(a0, bf1[n], acc[0][n], 0, 0, 0);
        acc[1][n] = __builtin_amdgcn_mfma_f32_16x16x32_bf16(a1, bf1[n], acc[1][n], 0, 0, 0);
        acc[2][n] = __builtin_amdgcn_mfma_f32_16x16x32_bf16(a2, bf1[n], acc[2][n], 0, 0, 0);
        acc[3][n] = __builtin_amdgcn_mfma_f32_16x16x32_bf16(a3, bf1[n], acc[3][n], 0, 0, 0);
      }
      __builtin_amdgcn_s_setprio(0);
    }

    if (more) stageA(kt + 1, 1);
    { // phase 3: m 4..7, ks 1 (reuse bf1)
      bf16x8 a0 = readA(b, 4, 1), a1 = readA(b, 5, 1), a2 = readA(b, 6, 1), a3 = readA(b, 7, 1);
      asm volatile("s_waitcnt lgkmcnt(0)" ::: "memory");
      __builtin_amdgcn_sched_barrier(0);
      __builtin_amdgcn_s_setprio(1);
      #pragma unroll
      for (int n = 0; n < 4; ++n) {
        acc[4][n] = __builtin_amdgcn_mfma_f32_16x16x32_bf16(a0, bf1[n], acc[4][n], 0, 0, 0);
        acc[5][n] = __builtin_amdgcn_mfma_f32_16x16x32_bf16(a1, bf1[n], acc[5][n], 0, 0, 0);
        acc[6][n] = __builtin_amdgcn_mfma_f32_16x16x32_bf16(a2, bf1[n], acc[6][n], 0, 0, 0);
        acc[7][n] = __builtin_amdgcn_mfma_f32_16x16x32_bf16(a3, bf1[n], acc[7][n], 0, 0, 0);
      }
      __builtin_amdgcn_s_setprio(0);
    }
  }

  // ---- epilogue (no LDS use; no barrier needed) ----
  #pragma unroll
  for (int m = 0; m < 8; ++m) {
    int rowb = row0 + wm * 128 + m * 16 + g * 4;
    #pragma unroll
    for (int n = 0; n < 4; ++n) {
      int col = col0 + wn * 64 + n * 16 + q16;
      f32x4 v = acc[m][n];
      if constexpr (EPI == 0) {
        int which = col >> 9, hd = col & 511;
        int hh = hd >> 6, dd = hd & 63;
        float bb = ((which == 0) ? bias0 : (which == 1) ? bias1 : bias2)[hd];
        if (which == 2) {
          int b_ = rowb >> 12, s0 = rowb & 4095;
          unsigned int lo = (unsigned)f2b(v[0] + bb) | ((unsigned)f2b(v[1] + bb) << 16);
          unsigned int hi = (unsigned)f2b(v[2] + bb) | ((unsigned)f2b(v[3] + bb) << 16);
          uint2 pv; pv.x = lo; pv.y = hi;
          *(uint2*)((char*)o2 + (((size_t)(b_ * 8 + hh) * 64 + dd) * 4096 + s0) * 2) = pv;
        } else {
          __hip_bfloat16* base = (__hip_bfloat16*)((which == 0) ? o0 : o1);
          #pragma unroll
          for (int r = 0; r < 4; ++r) {
            int rowg = rowb + r;
            int b_ = rowg >> 12, s = rowg & 4095;
            base[((size_t)(b_ * 8 + hh) * 4096 + s) * 64 + dd] = __float2bfloat16(v[r] + bb);
          }
        }
      } else {
        float bb = bias0[col];
        __hip_bfloat16* O = (__hip_bfloat16*)o0;
        #pragma unroll
        for (int r = 0; r < 4; ++r) {
          float x = v[r] + bb;
          if constexpr (EPI == 2) x = fmaxf(x, 0.f);
          O[(size_t)(rowb + r) * N + col] = __float2bfloat16(x);
        }
      }
    }
  }
}

// ---------------- BigBird sparse attention: R9 config (proven 49us) ----------------
// 8 waves key-split, ring-2 K/V, vmcnt(0)+barrier per tile, XCD-bijective swizzle.
#define NMID 1984
__global__ __launch_bounds__(512) void attn_k(
    const __hip_bfloat16* __restrict__ QB,
    const __hip_bfloat16* __restrict__ KB,
    const __hip_bfloat16* __restrict__ VT,
    const int* __restrict__ rand_attn,   // (8, 62, 3)
    __hip_bfloat16* __restrict__ CTX,    // (B, S, H*D)
    float* __restrict__ EOT,             // (512 chunks, 64 d, 64 q) fp32 partial O^T
    float* __restrict__ EML)             // (512 chunks, 64 q) fp32 partial l
{
  __shared__ __align__(16) char lK[2][8192];
  __shared__ __align__(16) char lV[2][8192];
  __shared__ __align__(16) char lP[4][2816];

  const int tid = threadIdx.x;
  const int wv = tid >> 6, ln = tid & 63;
  const int g = ln >> 4, q16 = ln & 15;
  const int kh = wv >> 2, qg = wv & 3;

  const int nwg = (int)gridDim.x;
  const int bid = (int)blockIdx.x;
  const int wg = (bid & 7) * (nwg >> 3) + (bid >> 3);

  const bool edge = wg >= NMID;
  int bh, l, nk, split = 0, chunk = 0;
  int r0 = 0, r1 = 0, r2 = 0;
  if (!edge) {
    bh = wg / 62;
    l = 1 + wg % 62;
    nk = (l == 1 || l == 62) ? 7 : 8;
    const int* rp = rand_attn + ((bh & 7) * 62 + (l - 1)) * 3;
    r0 = rp[0]; r1 = rp[1]; r2 = rp[2];
  } else {
    chunk = wg - NMID;
    split = chunk & 7;
    int be = chunk >> 3;
    bh = be >> 1;
    l = (be & 1) ? 63 : 0;
    nk = 8;
  }

  auto kbof = [&](int t) -> int {
    if (edge) return split * 8 + t;
    if (t == 0) return 0;
    if (t >= 4) return (t == 4) ? r0 : (t == 5) ? r1 : (t == 6) ? r2 : 63;
    if (l == 1) return (t == 3) ? 63 : t;   // [0,1,2,63]
    return l - 2 + t;                       // [0, l-1, l, l+1]
  };

  const __hip_bfloat16* Kbase = KB + ((size_t)bh << 18);
  const __hip_bfloat16* Vbase = VT + ((size_t)bh << 18);

  auto stage = [&](int t) {
    int kb = kbof(t);
    int o = wv * 1024 + ln * 16;
    int r = o >> 7;
    int sw8 = ((ln & 7) ^ (r & 7)) << 3;
    gload16(Kbase + ((size_t)(kb * 64 + r) << 6) + sw8, lK[t & 1] + wv * 1024);
    gload16(Vbase + ((size_t)r << 12) + kb * 64 + sw8, lV[t & 1] + wv * 1024);
  };

  const size_t sq = (size_t)bh * 4096 + l * 64 + qg * 16 + q16;
  bf16x8 qreg0 = *(const bf16x8*)(QB + sq * 64 + g * 8);
  bf16x8 qreg1 = *(const bf16x8*)(QB + sq * 64 + 32 + g * 8);

  f32x4 ot[4] = {};
  float l_part = 0.f;
  constexpr float C = 0.18033688011112042f;  // 0.125 * log2(e)

  auto compute = [&](int t) {
    const char* bK = lK[t & 1];
    const char* bV = lV[t & 1];
    f32x4 st[2];
    #pragma unroll
    for (int j = 0; j < 2; ++j) {
      int m = 2 * kh + j;
      int r = m * 16 + q16;
      bf16x8 kf0 = *(const bf16x8*)(bK + r * 128 + ((g ^ (r & 7)) << 4));
      bf16x8 kf1 = *(const bf16x8*)(bK + r * 128 + (((4 + g) ^ (r & 7)) << 4));
      f32x4 z = {};
      st[j] = __builtin_amdgcn_mfma_f32_16x16x32_bf16(kf0, qreg0, z, 0, 0, 0);
      st[j] = __builtin_amdgcn_mfma_f32_16x16x32_bf16(kf1, qreg1, st[j], 0, 0, 0);
    }
    #pragma unroll
    for (int j = 0; j < 2; ++j) {
      #pragma unroll
      for (int r = 0; r < 4; ++r) {
        float p = __builtin_amdgcn_exp2f(st[j][r] * C);
        st[j][r] = p;
        l_part += p;
      }
    }
    #pragma unroll
    for (int j = 0; j < 2; ++j) {
      int m = 2 * kh + j;
      unsigned int lo = (unsigned)f2b(st[j][0]) | ((unsigned)f2b(st[j][1]) << 16);
      unsigned int hi = (unsigned)f2b(st[j][2]) | ((unsigned)f2b(st[j][3]) << 16);
      uint2 pv; pv.x = lo; pv.y = hi;
      *(uint2*)(lP[qg] + q16 * 176 + 32 * m + 8 * g) = pv;
    }
    asm volatile("s_waitcnt lgkmcnt(0)" ::: "memory");
    __builtin_amdgcn_sched_barrier(0);
    bf16x8 pb = *(const bf16x8*)(lP[qg] + q16 * 176 + 64 * kh + 16 * g);
    #pragma unroll
    for (int m = 0; m < 4; ++m) {
      int r = m * 16 + q16;
      bf16x8 vf = *(const bf16x8*)(bV + r * 128 + (((4 * kh + g) ^ (r & 7)) << 4));
      ot[m] = __builtin_amdgcn_mfma_f32_16x16x32_bf16(vf, pb, ot[m], 0, 0, 0);
    }
  };

  stage(0);
  for (int t = 0; t < nk; ++t) {
    asm volatile("s_waitcnt vmcnt(0)" ::: "memory");
    __builtin_amdgcn_s_barrier();
    __builtin_amdgcn_sched_barrier(0);
    if (t + 1 < nk) stage(t + 1);
    compute(t);
  }

  float lsum = l_part;
  lsum += __shfl_xor(lsum, 16);
  lsum += __shfl_xor(lsum, 32);

  __builtin_amdgcn_s_barrier();   // all compute done; lK/lV dead
  float* red = (float*)lK;        // [16 vals][256 lanes] column-major: conflict-free
  float* lre = (float*)lV;        // [256]
  const int lane256 = qg * 64 + ln;
  if (kh == 1) {
    #pragma unroll
    for (int m = 0; m < 4; ++m)
      #pragma unroll
      for (int r = 0; r < 4; ++r)
        red[(4 * m + r) * 256 + lane256] = ot[m][r];
    lre[lane256] = lsum;
  }
  __syncthreads();
  if (kh == 0) {
    #pragma unroll
    for (int m = 0; m < 4; ++m)
      #pragma unroll
      for (int r = 0; r < 4; ++r)
        ot[m][r] += red[(4 * m + r) * 256 + lane256];
    lsum += lre[lane256];

    if (!edge) {
      int b = bh >> 3, h = bh & 7;
      float inv = 1.f / lsum;
      size_t crow = ((size_t)b * 4096 + l * 64 + qg * 16 + q16) * 512 + h * 64;
      #pragma unroll
      for (int m = 0; m < 4; ++m) {
        int d0 = 16 * m + 4 * g;
        unsigned int lo = (unsigned)f2b(ot[m][0] * inv) | ((unsigned)f2b(ot[m][1] * inv) << 16);
        unsigned int hi = (unsigned)f2b(ot[m][2] * inv) | ((unsigned)f2b(ot[m][3] * inv) << 16);
        uint2 pv; pv.x = lo; pv.y = hi;
        *(uint2*)((char*)CTX + (crow + d0) * 2) = pv;
      }
    } else {
      int qgl = qg * 16 + q16;
      float* O = EOT + (size_t)chunk * 4096;
      #pragma unroll
      for (int m = 0; m < 4; ++m)
        #pragma unroll
        for (int r = 0; r < 4; ++r)
          O[(16 * m + 4 * g + r) * 64 + qgl] = ot[m][r];
      if (g == 0) EML[(size_t)chunk * 64 + qgl] = lsum;
    }
  }
}

// ---------------- combine edge split-K partials (shared m=0) --------------
__global__ __launch_bounds__(256) void attn_combine_k(
    const float* __restrict__ EOT, const float* __restrict__ EML,
    __hip_bfloat16* __restrict__ CTX)
{
  const int be = blockIdx.x;
  const int bh = be >> 1, e = be & 1, b = bh >> 3, h = bh & 7;
  const int q = threadIdx.x & 63, dgrp = threadIdx.x >> 6;

  float denom = 0.f;
  #pragma unroll
  for (int s = 0; s < 8; ++s) denom += EML[(size_t)(be * 8 + s) * 64 + q];
  float inv = 1.f / denom;

  const size_t srow = (size_t)b * 4096 + (e ? 4032 : 0) + q;
  #pragma unroll
  for (int dd = 0; dd < 16; ++dd) {
    int d = dgrp * 16 + dd;
    float acc = 0.f;
    #pragma unroll
    for (int s = 0; s < 8; ++s)
      acc += EOT[(size_t)(be * 8 + s) * 4096 + d * 64 + q];
    CTX[srow * 512 + h * 64 + d] = __float2bfloat16(acc * inv);
  }
}

// ---------------- residual + LayerNorm (wave per row of 512) ----------------
template<typename TX, typename TY, bool OUTF, bool ADDY>
__global__ __launch_bounds__(256) void ln_k(
    const TX* __restrict__ X, const TY* __restrict__ Y,
    const float* __restrict__ gamma, const float* __restrict__ beta,
    float* __restrict__ outF, __hip_bfloat16* __restrict__ outB)
{
  const int wv = threadIdx.x >> 6, ln = threadIdx.x & 63;
  const size_t row = (size_t)blockIdx.x * 4 + wv;
  float v[8];
  {
    const TX* xr = X + row * 512 + ln * 8;
    if constexpr (sizeof(TX) == 4) {
      float4 a0 = *(const float4*)xr, a1 = *(const float4*)(xr + 4);
      v[0]=a0.x; v[1]=a0.y; v[2]=a0.z; v[3]=a0.w; v[4]=a1.x; v[5]=a1.y; v[6]=a1.z; v[7]=a1.w;
    } else {
      bf16x8 a = *(const bf16x8*)xr;
      #pragma unroll
      for (int i = 0; i < 8; ++i) v[i] = (float)a[i];
    }
    if constexpr (ADDY) {
      const TY* yr = Y + row * 512 + ln * 8;
      if constexpr (sizeof(TY) == 4) {
        float4 b0 = *(const float4*)yr, b1 = *(const float4*)(yr + 4);
        v[0]+=b0.x; v[1]+=b0.y; v[2]+=b0.z; v[3]+=b0.w; v[4]+=b1.x; v[5]+=b1.y; v[6]+=b1.z; v[7]+=b1.w;
      } else {
        bf16x8 bv_ = *(const bf16x8*)yr;
        #pragma unroll
        for (int i = 0; i < 8; ++i) v[i] += (float)bv_[i];
      }
    }
  }
  float s = 0.f;
  #pragma unroll
  for (int i = 0; i < 8; ++i) s += v[i];
  #pragma unroll
  for (int o = 1; o < 64; o <<= 1) s += __shfl_xor(s, o);
  float mean = s * (1.f / 512.f);
  float sq = 0.f;
  #pragma unroll
  for (int i = 0; i < 8; ++i) { float d = v[i] - mean; sq += d * d; }
  #pragma unroll
  for (int o = 1; o < 64; o <<= 1) sq += __shfl_xor(sq, o);
  float rs = rsqrtf(sq * (1.f / 512.f) + 1e-6f);
  float og[8];
  #pragma unroll
  for (int i = 0; i < 8; ++i)
    og[i] = (v[i] - mean) * rs * gamma[ln * 8 + i] + beta[ln * 8 + i];
  if constexpr (OUTF) {
    float4 o0; o0.x = og[0]; o0.y = og[1]; o0.z = og[2]; o0.w = og[3];
    float4 o1; o1.x = og[4]; o1.y = og[5]; o1.z = og[6]; o1.w = og[7];
    *(float4*)(outF + row * 512 + ln * 8) = o0;
    *(float4*)(outF + row * 512 + ln * 8 + 4) = o1;
  } else {
    unsigned int w0 = (unsigned)f2b(og[0]) | ((unsigned)f2b(og[1]) << 16);
    unsigned int w1 = (unsigned)f2b(og[2]) | ((unsigned)f2b(og[3]) << 16);
    unsigned int w2 = (unsigned)f2b(og[4]) | ((unsigned)f2b(og[5]) << 16);
    unsigned int w3 = (unsigned)f2b(og[6]) | ((unsigned)f2b(og[7]) << 16);
    uint2 p0; p0.x = w0; p0.y = w1;
    uint2 p1; p1.x = w2; p1.y = w3;
    *(uint2*)((char*)outB + (row * 512 + ln * 8) * 2) = p0;
    *(uint2*)((char*)outB + (row * 512 + ln * 8 + 4) * 2) = p1;
  }
}

extern "C" void kernel_launch(void* const* d_in, const int* in_sizes, int n_in,
                              void* d_out, int out_size, void* d_ws, size_t ws_size,
                              hipStream_t stream)
{
  (void)in_sizes; (void)n_in; (void)out_size; (void)ws_size;
  const float* X   = (const float*)d_in[0];
  const float* Wq  = (const float*)d_in[5];
  const float* bq  = (const float*)d_in[6];
  const float* Wk  = (const float*)d_in[7];
  const float* bk  = (const float*)d_in[8];
  const float* Wv  = (const float*)d_in[9];
  const float* bv  = (const float*)d_in[10];
  const float* Wo  = (const float*)d_in[11];
  const float* bo  = (const float*)d_in[12];
  const float* W1  = (const float*)d_in[13];
  const float* b1  = (const float*)d_in[14];
  const float* W2  = (const float*)d_in[15];
  const float* b2  = (const float*)d_in[16];
  const float* g1  = (const float*)d_in[17];
  const float* be1 = (const float*)d_in[18];
  const float* g2  = (const float*)d_in[19];
  const float* be2 = (const float*)d_in[20];
  const int*   ra  = (const int*)d_in[21];

  char* ws = (char*)d_ws;
  __hip_bfloat16* WQKVT = (__hip_bfloat16*)(ws + 0 * MB);    // 1.5 MB
  __hip_bfloat16* WOT   = (__hip_bfloat16*)(ws + 2 * MB);    // 0.5 MB
  __hip_bfloat16* W1T   = (__hip_bfloat16*)(ws + 3 * MB);    // 2 MB
  __hip_bfloat16* W2T   = (__hip_bfloat16*)(ws + 5 * MB);    // 2 MB (ends 7 MB)
  __hip_bfloat16* XB    = (__hip_bfloat16*)(ws + 8 * MB);    // 16 MB (alive through LN1)
  __hip_bfloat16* QB    = (__hip_bfloat16*)(ws + 24 * MB);   // 16 MB (dead after attn)
  __hip_bfloat16* KBp   = (__hip_bfloat16*)(ws + 40 * MB);   // 16 MB (dead after attn)
  __hip_bfloat16* VTp   = (__hip_bfloat16*)(ws + 56 * MB);   // 16 MB (dead after attn)
  __hip_bfloat16* CTX   = (__hip_bfloat16*)(ws + 72 * MB);   // 16 MB (dead after Wo gemm)
  __hip_bfloat16* AOB   = (__hip_bfloat16*)(ws + 88 * MB);   // 16 MB bf16 attn-out
  __hip_bfloat16* O1B   = (__hip_bfloat16*)(ws + 104 * MB);  // 16 MB bf16 LN1-out
  __hip_bfloat16* S2B   = (__hip_bfloat16*)(ws + 120 * MB);  // 16 MB bf16 (O1+FFN2)
  float*          EOT   = (float*)(ws + 136 * MB);           // 8 MB
  float*          EML   = (float*)(ws + 144 * MB);           // 128 KB -> peak ~144.2 MB
  __hip_bfloat16* H1    = (__hip_bfloat16*)(ws + 24 * MB);   // 64 MB, reuses QB/KB/VT/CTX (dead)

  pt_k<<<dim3(4864), dim3(256), 0, stream>>>(X, Wq, Wk, Wv, Wo, W1, W2,
                                             XB, WQKVT, WOT, W1T, W2T);
  gemm256_k<0><<<dim3(64 * 6), dim3(512), 0, stream>>>(XB, WQKVT, 16384, 1536, 512,
                                                       bq, bk, bv, QB, KBp, VTp);
  attn_k<<<dim3(NMID + 512), dim3(512), 0, stream>>>(QB, KBp, VTp, ra, CTX, EOT, EML);
  attn_combine_k<<<dim3(64), dim3(256), 0, stream>>>(EOT, EML, CTX);
  gemm_k<1><<<dim3(128 * 4), dim3(256), 0, stream>>>(CTX, WOT, 16384, 512, 512,
                                                     bo, nullptr, AOB);
  ln_k<__hip_bfloat16, __hip_bfloat16, false, true><<<dim3(4096), dim3(256), 0, stream>>>(
      XB, AOB, g1, be1, nullptr, O1B);
  gemm256_k<2><<<dim3(64 * 8), dim3(512), 0, stream>>>(O1B, W1T, 16384, 2048, 512,
                                                       b1, nullptr, nullptr, H1, nullptr, nullptr);
  gemm_k<3><<<dim3(128 * 4), dim3(256), 0, stream>>>(H1, W2T, 16384, 512, 2048,
                                                     b2, O1B, S2B);
  ln_k<__hip_bfloat16, __hip_bfloat16, true, false><<<dim3(4096), dim3(256), 0, stream>>>(
      S2B, nullptr, g2, be2, (float*)d_out, nullptr);
}

// Round 14
// 234.933 us; speedup vs baseline: 1.0426x; 1.0426x over previous
//
#include <hip/hip_runtime.h>
#include <hip/hip_bf16.h>

typedef __bf16 bf16x8 __attribute__((ext_vector_type(8)));
typedef float f32x4 __attribute__((ext_vector_type(4)));

static constexpr size_t MB = 1024 * 1024;

__device__ __forceinline__ void gload16(const void* g, void* l) {
  __builtin_amdgcn_global_load_lds((const __attribute__((address_space(1))) unsigned int*)g,
                                   (__attribute__((address_space(3))) unsigned int*)l,
                                   16, 0, 0);
}

__device__ __forceinline__ unsigned short f2b(float x) {
  union { __hip_bfloat16 h; unsigned short u; } cv;
  cv.h = __float2bfloat16(x);
  return cv.u;
}

// ------------- pack/transpose: X -> bf16 (vectorized) + tiled weight transposes -------------
__global__ __launch_bounds__(256) void pt_k(
    const float* __restrict__ X,
    const float* __restrict__ Wq, const float* __restrict__ Wk, const float* __restrict__ Wv,
    const float* __restrict__ Wo, const float* __restrict__ W1, const float* __restrict__ W2,
    __hip_bfloat16* __restrict__ XB, __hip_bfloat16* __restrict__ WQKVT,
    __hip_bfloat16* __restrict__ WOT, __hip_bfloat16* __restrict__ W1T,
    __hip_bfloat16* __restrict__ W2T)
{
  __shared__ float tile[64][65];
  const int bid = blockIdx.x, tid = threadIdx.x;
  if (bid < 4096) {
    size_t i = (size_t)bid * 2048 + tid * 8;
    float4 a0 = *(const float4*)(X + i);
    float4 a1 = *(const float4*)(X + i + 4);
    unsigned int w0 = (unsigned)f2b(a0.x) | ((unsigned)f2b(a0.y) << 16);
    unsigned int w1 = (unsigned)f2b(a0.z) | ((unsigned)f2b(a0.w) << 16);
    unsigned int w2 = (unsigned)f2b(a1.x) | ((unsigned)f2b(a1.y) << 16);
    unsigned int w3 = (unsigned)f2b(a1.z) | ((unsigned)f2b(a1.w) << 16);
    uint4 p; p.x = w0; p.y = w1; p.z = w2; p.w = w3;
    *(uint4*)(XB + i) = p;
    return;
  }
  int tb = bid - 4096;
  const float* in; __hip_bfloat16* out; int R, C, tt;
  if (tb < 64)       { in = Wq; out = WQKVT;          R = 512;  C = 512;  tt = tb; }
  else if (tb < 128) { in = Wk; out = WQKVT + 262144; R = 512;  C = 512;  tt = tb - 64; }
  else if (tb < 192) { in = Wv; out = WQKVT + 524288; R = 512;  C = 512;  tt = tb - 128; }
  else if (tb < 256) { in = Wo; out = WOT;            R = 512;  C = 512;  tt = tb - 192; }
  else if (tb < 512) { in = W1; out = W1T;            R = 512;  C = 2048; tt = tb - 256; }
  else               { in = W2; out = W2T;            R = 2048; C = 512;  tt = tb - 512; }
  const int ct = C >> 6;
  const int r0 = (tt / ct) << 6, c0 = (tt % ct) << 6;
  const int tx = tid & 63, ty = tid >> 6;
  #pragma unroll
  for (int j = 0; j < 16; ++j) {
    int r = ty * 16 + j;
    tile[r][tx] = in[(size_t)(r0 + r) * C + c0 + tx];
  }
  __syncthreads();
  #pragma unroll
  for (int j = 0; j < 16; ++j) {
    int c = ty * 16 + j;
    out[(size_t)(c0 + c) * R + r0 + tx] = __float2bfloat16(tile[tx][c]);
  }
}

// ---------------- 128x128 bf16 MFMA GEMM, BK=64, 4 waves, epilogue-templated ----------------
// EPI 0: QKV scatter; EPI 1: +bias -> bf16; EPI 2: +bias+relu -> bf16;
// EPI 3: +bias+residual(bf16) -> bf16.
// Default bid->(bm,bn) mapping: with mT%8==0 the round-robin XCD assignment
// partitions A rows as bm%8 -> stable 2MB A-slice per L2. (R8's explicit XCD
// swizzle destroyed this: FETCH 133MB vs ~25MB. R13's 256^2 8-phase also lost:
// 58 vs 49us, both pipes idle at gates. This structure is the measured optimum.)
template<int EPI>
__global__ __launch_bounds__(256) void gemm_k(
    const __hip_bfloat16* __restrict__ A,
    const __hip_bfloat16* __restrict__ Bt,
    int M, int N, int K,
    const float* __restrict__ bias0, const float* __restrict__ bias1, const float* __restrict__ bias2,
    const __hip_bfloat16* __restrict__ resid,
    void* __restrict__ o0, void* __restrict__ o1, void* __restrict__ o2)
{
  __shared__ __align__(16) char lA[128 * 64 * 2];
  __shared__ __align__(16) char lB[128 * 64 * 2];
  const int tid = threadIdx.x;
  const int wv = tid >> 6, ln = tid & 63;
  const int g = ln >> 4, q16 = ln & 15;
  const int mT = M >> 7;
  const int bm = blockIdx.x % mT, bn = blockIdx.x / mT;
  const int row0 = bm << 7, col0 = bn << 7;
  const int wm = wv >> 1, wn = wv & 1;
  const int ktn = K >> 6;

  f32x4 acc[4][4] = {};

  for (int kt = 0; kt < ktn; ++kt) {
    #pragma unroll
    for (int c4 = 0; c4 < 4; ++c4) {
      int c = wv * 4 + c4;
      int o = c * 1024 + ln * 16;
      int r = o >> 7;
      int slot = (o >> 4) & 7;
      int koff = kt * 64 + ((slot ^ (r & 7)) << 3);
      gload16(A + (size_t)(row0 + r) * K + koff, lA + c * 1024);
      gload16(Bt + (size_t)(col0 + r) * K + koff, lB + c * 1024);
    }
    __syncthreads();
    #pragma unroll
    for (int ks = 0; ks < 2; ++ks) {
      bf16x8 af[4], bfr[4];
      #pragma unroll
      for (int m = 0; m < 4; ++m) {
        int r = wm * 64 + m * 16 + q16;
        af[m] = *(const bf16x8*)(lA + r * 128 + (((4 * ks + g) ^ (r & 7)) << 4));
      }
      #pragma unroll
      for (int n = 0; n < 4; ++n) {
        int r = wn * 64 + n * 16 + q16;
        bfr[n] = *(const bf16x8*)(lB + r * 128 + (((4 * ks + g) ^ (r & 7)) << 4));
      }
      #pragma unroll
      for (int m = 0; m < 4; ++m) {
        #pragma unroll
        for (int n = 0; n < 4; ++n) {
          acc[m][n] = __builtin_amdgcn_mfma_f32_16x16x32_bf16(af[m], bfr[n], acc[m][n], 0, 0, 0);
        }
      }
    }
    __syncthreads();
  }

  #pragma unroll
  for (int m = 0; m < 4; ++m) {
    int rowb = row0 + wm * 64 + m * 16 + g * 4;
    #pragma unroll
    for (int n = 0; n < 4; ++n) {
      int col = col0 + wn * 64 + n * 16 + q16;
      f32x4 v = acc[m][n];
      if constexpr (EPI == 0) {
        int which = col >> 9, hd = col & 511;
        int hh = hd >> 6, dd = hd & 63;
        float bb = ((which == 0) ? bias0 : (which == 1) ? bias1 : bias2)[hd];
        if (which == 2) {
          int b_ = rowb >> 12, s0 = rowb & 4095;
          unsigned int lo = (unsigned)f2b(v[0] + bb) | ((unsigned)f2b(v[1] + bb) << 16);
          unsigned int hi = (unsigned)f2b(v[2] + bb) | ((unsigned)f2b(v[3] + bb) << 16);
          uint2 pv; pv.x = lo; pv.y = hi;
          *(uint2*)((char*)o2 + (((size_t)(b_ * 8 + hh) * 64 + dd) * 4096 + s0) * 2) = pv;
        } else {
          __hip_bfloat16* base = (__hip_bfloat16*)((which == 0) ? o0 : o1);
          #pragma unroll
          for (int r = 0; r < 4; ++r) {
            int rowg = rowb + r;
            int b_ = rowg >> 12, s = rowg & 4095;
            base[((size_t)(b_ * 8 + hh) * 4096 + s) * 64 + dd] = __float2bfloat16(v[r] + bb);
          }
        }
      } else {
        float bb = bias0[col];
        __hip_bfloat16* O = (__hip_bfloat16*)o0;
        #pragma unroll
        for (int r = 0; r < 4; ++r) {
          float x = v[r] + bb;
          if constexpr (EPI == 2) x = fmaxf(x, 0.f);
          if constexpr (EPI == 3) x += (float)resid[(size_t)(rowb + r) * N + col];
          O[(size_t)(rowb + r) * N + col] = __float2bfloat16(x);
        }
      }
    }
  }
}

// ---------------- BigBird sparse attention: R9 config (proven 49us) ----------------
// 8 waves key-split, ring-2 K/V, vmcnt(0)+barrier per tile, XCD-bijective swizzle.
// (Ring-3 counted vmcnt measured -10% (R11): occupancy loss beats latency hiding here.)
#define NMID 1984
__global__ __launch_bounds__(512) void attn_k(
    const __hip_bfloat16* __restrict__ QB,
    const __hip_bfloat16* __restrict__ KB,
    const __hip_bfloat16* __restrict__ VT,
    const int* __restrict__ rand_attn,   // (8, 62, 3)
    __hip_bfloat16* __restrict__ CTX,    // (B, S, H*D)
    float* __restrict__ EOT,             // (512 chunks, 64 d, 64 q) fp32 partial O^T
    float* __restrict__ EML)             // (512 chunks, 64 q) fp32 partial l
{
  __shared__ __align__(16) char lK[2][8192];
  __shared__ __align__(16) char lV[2][8192];
  __shared__ __align__(16) char lP[4][2816];

  const int tid = threadIdx.x;
  const int wv = tid >> 6, ln = tid & 63;
  const int g = ln >> 4, q16 = ln & 15;
  const int kh = wv >> 2, qg = wv & 3;

  const int nwg = (int)gridDim.x;
  const int bid = (int)blockIdx.x;
  const int wg = (bid & 7) * (nwg >> 3) + (bid >> 3);

  const bool edge = wg >= NMID;
  int bh, l, nk, split = 0, chunk = 0;
  int r0 = 0, r1 = 0, r2 = 0;
  if (!edge) {
    bh = wg / 62;
    l = 1 + wg % 62;
    nk = (l == 1 || l == 62) ? 7 : 8;
    const int* rp = rand_attn + ((bh & 7) * 62 + (l - 1)) * 3;
    r0 = rp[0]; r1 = rp[1]; r2 = rp[2];
  } else {
    chunk = wg - NMID;
    split = chunk & 7;
    int be = chunk >> 3;
    bh = be >> 1;
    l = (be & 1) ? 63 : 0;
    nk = 8;
  }

  auto kbof = [&](int t) -> int {
    if (edge) return split * 8 + t;
    if (t == 0) return 0;
    if (t >= 4) return (t == 4) ? r0 : (t == 5) ? r1 : (t == 6) ? r2 : 63;
    if (l == 1) return (t == 3) ? 63 : t;   // [0,1,2,63]
    return l - 2 + t;                       // [0, l-1, l, l+1]
  };

  const __hip_bfloat16* Kbase = KB + ((size_t)bh << 18);
  const __hip_bfloat16* Vbase = VT + ((size_t)bh << 18);

  auto stage = [&](int t) {
    int kb = kbof(t);
    int o = wv * 1024 + ln * 16;
    int r = o >> 7;
    int sw8 = ((ln & 7) ^ (r & 7)) << 3;
    gload16(Kbase + ((size_t)(kb * 64 + r) << 6) + sw8, lK[t & 1] + wv * 1024);
    gload16(Vbase + ((size_t)r << 12) + kb * 64 + sw8, lV[t & 1] + wv * 1024);
  };

  const size_t sq = (size_t)bh * 4096 + l * 64 + qg * 16 + q16;
  bf16x8 qreg0 = *(const bf16x8*)(QB + sq * 64 + g * 8);
  bf16x8 qreg1 = *(const bf16x8*)(QB + sq * 64 + 32 + g * 8);

  f32x4 ot[4] = {};
  float l_part = 0.f;
  constexpr float C = 0.18033688011112042f;  // 0.125 * log2(e)

  auto compute = [&](int t) {
    const char* bK = lK[t & 1];
    const char* bV = lV[t & 1];
    f32x4 st[2];
    #pragma unroll
    for (int j = 0; j < 2; ++j) {
      int m = 2 * kh + j;
      int r = m * 16 + q16;
      bf16x8 kf0 = *(const bf16x8*)(bK + r * 128 + ((g ^ (r & 7)) << 4));
      bf16x8 kf1 = *(const bf16x8*)(bK + r * 128 + (((4 + g) ^ (r & 7)) << 4));
      f32x4 z = {};
      st[j] = __builtin_amdgcn_mfma_f32_16x16x32_bf16(kf0, qreg0, z, 0, 0, 0);
      st[j] = __builtin_amdgcn_mfma_f32_16x16x32_bf16(kf1, qreg1, st[j], 0, 0, 0);
    }
    #pragma unroll
    for (int j = 0; j < 2; ++j) {
      #pragma unroll
      for (int r = 0; r < 4; ++r) {
        float p = __builtin_amdgcn_exp2f(st[j][r] * C);
        st[j][r] = p;
        l_part += p;
      }
    }
    #pragma unroll
    for (int j = 0; j < 2; ++j) {
      int m = 2 * kh + j;
      unsigned int lo = (unsigned)f2b(st[j][0]) | ((unsigned)f2b(st[j][1]) << 16);
      unsigned int hi = (unsigned)f2b(st[j][2]) | ((unsigned)f2b(st[j][3]) << 16);
      uint2 pv; pv.x = lo; pv.y = hi;
      *(uint2*)(lP[qg] + q16 * 176 + 32 * m + 8 * g) = pv;
    }
    asm volatile("s_waitcnt lgkmcnt(0)" ::: "memory");
    __builtin_amdgcn_sched_barrier(0);
    bf16x8 pb = *(const bf16x8*)(lP[qg] + q16 * 176 + 64 * kh + 16 * g);
    #pragma unroll
    for (int m = 0; m < 4; ++m) {
      int r = m * 16 + q16;
      bf16x8 vf = *(const bf16x8*)(bV + r * 128 + (((4 * kh + g) ^ (r & 7)) << 4));
      ot[m] = __builtin_amdgcn_mfma_f32_16x16x32_bf16(vf, pb, ot[m], 0, 0, 0);
    }
  };

  stage(0);
  for (int t = 0; t < nk; ++t) {
    asm volatile("s_waitcnt vmcnt(0)" ::: "memory");
    __builtin_amdgcn_s_barrier();
    __builtin_amdgcn_sched_barrier(0);
    if (t + 1 < nk) stage(t + 1);
    compute(t);
  }

  float lsum = l_part;
  lsum += __shfl_xor(lsum, 16);
  lsum += __shfl_xor(lsum, 32);

  __builtin_amdgcn_s_barrier();   // all compute done; lK/lV dead
  float* red = (float*)lK;        // [16 vals][256 lanes] column-major: conflict-free
  float* lre = (float*)lV;        // [256]
  const int lane256 = qg * 64 + ln;
  if (kh == 1) {
    #pragma unroll
    for (int m = 0; m < 4; ++m)
      #pragma unroll
      for (int r = 0; r < 4; ++r)
        red[(4 * m + r) * 256 + lane256] = ot[m][r];
    lre[lane256] = lsum;
  }
  __syncthreads();
  if (kh == 0) {
    #pragma unroll
    for (int m = 0; m < 4; ++m)
      #pragma unroll
      for (int r = 0; r < 4; ++r)
        ot[m][r] += red[(4 * m + r) * 256 + lane256];
    lsum += lre[lane256];

    if (!edge) {
      int b = bh >> 3, h = bh & 7;
      float inv = 1.f / lsum;
      size_t crow = ((size_t)b * 4096 + l * 64 + qg * 16 + q16) * 512 + h * 64;
      #pragma unroll
      for (int m = 0; m < 4; ++m) {
        int d0 = 16 * m + 4 * g;
        unsigned int lo = (unsigned)f2b(ot[m][0] * inv) | ((unsigned)f2b(ot[m][1] * inv) << 16);
        unsigned int hi = (unsigned)f2b(ot[m][2] * inv) | ((unsigned)f2b(ot[m][3] * inv) << 16);
        uint2 pv; pv.x = lo; pv.y = hi;
        *(uint2*)((char*)CTX + (crow + d0) * 2) = pv;
      }
    } else {
      int qgl = qg * 16 + q16;
      float* O = EOT + (size_t)chunk * 4096;
      #pragma unroll
      for (int m = 0; m < 4; ++m)
        #pragma unroll
        for (int r = 0; r < 4; ++r)
          O[(16 * m + 4 * g + r) * 64 + qgl] = ot[m][r];
      if (g == 0) EML[(size_t)chunk * 64 + qgl] = lsum;
    }
  }
}

// ---------------- combine edge split-K partials (shared m=0) --------------
__global__ __launch_bounds__(256) void attn_combine_k(
    const float* __restrict__ EOT, const float* __restrict__ EML,
    __hip_bfloat16* __restrict__ CTX)
{
  const int be = blockIdx.x;
  const int bh = be >> 1, e = be & 1, b = bh >> 3, h = bh & 7;
  const int q = threadIdx.x & 63, dgrp = threadIdx.x >> 6;

  float denom = 0.f;
  #pragma unroll
  for (int s = 0; s < 8; ++s) denom += EML[(size_t)(be * 8 + s) * 64 + q];
  float inv = 1.f / denom;

  const size_t srow = (size_t)b * 4096 + (e ? 4032 : 0) + q;
  #pragma unroll
  for (int dd = 0; dd < 16; ++dd) {
    int d = dgrp * 16 + dd;
    float acc = 0.f;
    #pragma unroll
    for (int s = 0; s < 8; ++s)
      acc += EOT[(size_t)(be * 8 + s) * 4096 + d * 64 + q];
    CTX[srow * 512 + h * 64 + d] = __float2bfloat16(acc * inv);
  }
}

// ---------------- residual + LayerNorm (wave per row of 512) ----------------
template<typename TX, typename TY, bool OUTF, bool ADDY>
__global__ __launch_bounds__(256) void ln_k(
    const TX* __restrict__ X, const TY* __restrict__ Y,
    const float* __restrict__ gamma, const float* __restrict__ beta,
    float* __restrict__ outF, __hip_bfloat16* __restrict__ outB)
{
  const int wv = threadIdx.x >> 6, ln = threadIdx.x & 63;
  const size_t row = (size_t)blockIdx.x * 4 + wv;
  float v[8];
  {
    const TX* xr = X + row * 512 + ln * 8;
    if constexpr (sizeof(TX) == 4) {
      float4 a0 = *(const float4*)xr, a1 = *(const float4*)(xr + 4);
      v[0]=a0.x; v[1]=a0.y; v[2]=a0.z; v[3]=a0.w; v[4]=a1.x; v[5]=a1.y; v[6]=a1.z; v[7]=a1.w;
    } else {
      bf16x8 a = *(const bf16x8*)xr;
      #pragma unroll
      for (int i = 0; i < 8; ++i) v[i] = (float)a[i];
    }
    if constexpr (ADDY) {
      const TY* yr = Y + row * 512 + ln * 8;
      if constexpr (sizeof(TY) == 4) {
        float4 b0 = *(const float4*)yr, b1 = *(const float4*)(yr + 4);
        v[0]+=b0.x; v[1]+=b0.y; v[2]+=b0.z; v[3]+=b0.w; v[4]+=b1.x; v[5]+=b1.y; v[6]+=b1.z; v[7]+=b1.w;
      } else {
        bf16x8 bv_ = *(const bf16x8*)yr;
        #pragma unroll
        for (int i = 0; i < 8; ++i) v[i] += (float)bv_[i];
      }
    }
  }
  float s = 0.f;
  #pragma unroll
  for (int i = 0; i < 8; ++i) s += v[i];
  #pragma unroll
  for (int o = 1; o < 64; o <<= 1) s += __shfl_xor(s, o);
  float mean = s * (1.f / 512.f);
  float sq = 0.f;
  #pragma unroll
  for (int i = 0; i < 8; ++i) { float d = v[i] - mean; sq += d * d; }
  #pragma unroll
  for (int o = 1; o < 64; o <<= 1) sq += __shfl_xor(sq, o);
  float rs = rsqrtf(sq * (1.f / 512.f) + 1e-6f);
  float og[8];
  #pragma unroll
  for (int i = 0; i < 8; ++i)
    og[i] = (v[i] - mean) * rs * gamma[ln * 8 + i] + beta[ln * 8 + i];
  if constexpr (OUTF) {
    float4 o0; o0.x = og[0]; o0.y = og[1]; o0.z = og[2]; o0.w = og[3];
    float4 o1; o1.x = og[4]; o1.y = og[5]; o1.z = og[6]; o1.w = og[7];
    *(float4*)(outF + row * 512 + ln * 8) = o0;
    *(float4*)(outF + row * 512 + ln * 8 + 4) = o1;
  } else {
    unsigned int w0 = (unsigned)f2b(og[0]) | ((unsigned)f2b(og[1]) << 16);
    unsigned int w1 = (unsigned)f2b(og[2]) | ((unsigned)f2b(og[3]) << 16);
    unsigned int w2 = (unsigned)f2b(og[4]) | ((unsigned)f2b(og[5]) << 16);
    unsigned int w3 = (unsigned)f2b(og[6]) | ((unsigned)f2b(og[7]) << 16);
    uint2 p0; p0.x = w0; p0.y = w1;
    uint2 p1; p1.x = w2; p1.y = w3;
    *(uint2*)((char*)outB + (row * 512 + ln * 8) * 2) = p0;
    *(uint2*)((char*)outB + (row * 512 + ln * 8 + 4) * 2) = p1;
  }
}

extern "C" void kernel_launch(void* const* d_in, const int* in_sizes, int n_in,
                              void* d_out, int out_size, void* d_ws, size_t ws_size,
                              hipStream_t stream)
{
  (void)in_sizes; (void)n_in; (void)out_size; (void)ws_size;
  const float* X   = (const float*)d_in[0];
  const float* Wq  = (const float*)d_in[5];
  const float* bq  = (const float*)d_in[6];
  const float* Wk  = (const float*)d_in[7];
  const float* bk  = (const float*)d_in[8];
  const float* Wv  = (const float*)d_in[9];
  const float* bv  = (const float*)d_in[10];
  const float* Wo  = (const float*)d_in[11];
  const float* bo  = (const float*)d_in[12];
  const float* W1  = (const float*)d_in[13];
  const float* b1  = (const float*)d_in[14];
  const float* W2  = (const float*)d_in[15];
  const float* b2  = (const float*)d_in[16];
  const float* g1  = (const float*)d_in[17];
  const float* be1 = (const float*)d_in[18];
  const float* g2  = (const float*)d_in[19];
  const float* be2 = (const float*)d_in[20];
  const int*   ra  = (const int*)d_in[21];

  char* ws = (char*)d_ws;
  __hip_bfloat16* WQKVT = (__hip_bfloat16*)(ws + 0 * MB);    // 1.5 MB
  __hip_bfloat16* WOT   = (__hip_bfloat16*)(ws + 2 * MB);    // 0.5 MB
  __hip_bfloat16* W1T   = (__hip_bfloat16*)(ws + 3 * MB);    // 2 MB
  __hip_bfloat16* W2T   = (__hip_bfloat16*)(ws + 5 * MB);    // 2 MB (ends 7 MB)
  __hip_bfloat16* XB    = (__hip_bfloat16*)(ws + 8 * MB);    // 16 MB (alive through LN1)
  __hip_bfloat16* QB    = (__hip_bfloat16*)(ws + 24 * MB);   // 16 MB (dead after attn)
  __hip_bfloat16* KBp   = (__hip_bfloat16*)(ws + 40 * MB);   // 16 MB (dead after attn)
  __hip_bfloat16* VTp   = (__hip_bfloat16*)(ws + 56 * MB);   // 16 MB (dead after attn)
  __hip_bfloat16* CTX   = (__hip_bfloat16*)(ws + 72 * MB);   // 16 MB (dead after Wo gemm)
  __hip_bfloat16* AOB   = (__hip_bfloat16*)(ws + 88 * MB);   // 16 MB bf16 attn-out
  __hip_bfloat16* O1B   = (__hip_bfloat16*)(ws + 104 * MB);  // 16 MB bf16 LN1-out
  __hip_bfloat16* S2B   = (__hip_bfloat16*)(ws + 120 * MB);  // 16 MB bf16 (O1+FFN2)
  float*          EOT   = (float*)(ws + 136 * MB);           // 8 MB
  float*          EML   = (float*)(ws + 144 * MB);           // 128 KB -> peak ~144.2 MB
  __hip_bfloat16* H1    = (__hip_bfloat16*)(ws + 24 * MB);   // 64 MB, reuses QB/KB/VT/CTX (dead)

  pt_k<<<dim3(4864), dim3(256), 0, stream>>>(X, Wq, Wk, Wv, Wo, W1, W2,
                                             XB, WQKVT, WOT, W1T, W2T);
  gemm_k<0><<<dim3(128 * 12), dim3(256), 0, stream>>>(XB, WQKVT, 16384, 1536, 512,
                                                      bq, bk, bv, nullptr, QB, KBp, VTp);
  attn_k<<<dim3(NMID + 512), dim3(512), 0, stream>>>(QB, KBp, VTp, ra, CTX, EOT, EML);
  attn_combine_k<<<dim3(64), dim3(256), 0, stream>>>(EOT, EML, CTX);
  gemm_k<1><<<dim3(128 * 4), dim3(256), 0, stream>>>(CTX, WOT, 16384, 512, 512,
                                                     bo, nullptr, nullptr, nullptr, AOB, nullptr, nullptr);
  ln_k<__hip_bfloat16, __hip_bfloat16, false, true><<<dim3(4096), dim3(256), 0, stream>>>(
      XB, AOB, g1, be1, nullptr, O1B);
  gemm_k<2><<<dim3(128 * 16), dim3(256), 0, stream>>>(O1B, W1T, 16384, 2048, 512,
                                                      b1, nullptr, nullptr, nullptr, H1, nullptr, nullptr);
  gemm_k<3><<<dim3(128 * 4), dim3(256), 0, stream>>>(H1, W2T, 16384, 512, 2048,
                                                     b2, nullptr, nullptr, O1B, S2B, nullptr, nullptr);
  ln_k<__hip_bfloat16, __hip_bfloat16, true, false><<<dim3(4096), dim3(256), 0, stream>>>(
      S2B, nullptr, g2, be2, (float*)d_out, nullptr);
}